// Round 1
// baseline (317.021 us; speedup 1.0000x reference)
//
#include <hip/hip_runtime.h>
#include <hip/hip_bf16.h>

#define OUT_CH 4096
#define IN_FEAT 11008
#define EPS 1e-5f
#define BIT_BOUND 6.0f

// One block per output channel (row). Row scalars (scale, bit) loaded once,
// broadcast via scalar cache. float4-vectorized body: IN_FEAT/4 = 2752 vec4
// per row, 256 threads -> 10.75 iters.
__global__ __launch_bounds__(256) void fake_quant_kernel(
    const float* __restrict__ weight,
    const float* __restrict__ alh,
    const float* __restrict__ bit,
    float* __restrict__ out)
{
    const int row = blockIdx.x;
    if (row >= OUT_CH) return;

    // Per-row quant params (forward values; STE affects only gradients).
    const float s = fmaxf(alh[row], EPS);
    const float b_eff = fminf(fmaxf(fabsf(bit[row]), 1.0f), BIT_BOUND);
    const float b_r = rintf(b_eff);                       // jnp.round = half-to-even
    const float qmax = fmaxf(exp2f(b_r - 1.0f) - 1.0f, 1.0f);
    const float qmin = -qmax;

    const float4* __restrict__ wrow =
        (const float4*)(weight + (size_t)row * IN_FEAT);
    float4* __restrict__ orow = (float4*)(out + (size_t)row * IN_FEAT);

    const int nvec = IN_FEAT / 4;  // 2752
    for (int i = threadIdx.x; i < nvec; i += blockDim.x) {
        float4 w = wrow[i];
        float4 r;
        // Exact division (matches np w/scale); rintf = round-half-even.
        r.x = fminf(fmaxf(rintf(w.x / s), qmin), qmax) * s;
        r.y = fminf(fmaxf(rintf(w.y / s), qmin), qmax) * s;
        r.z = fminf(fmaxf(rintf(w.z / s), qmin), qmax) * s;
        r.w = fminf(fmaxf(rintf(w.w / s), qmin), qmax) * s;
        orow[i] = r;
    }
}

extern "C" void kernel_launch(void* const* d_in, const int* in_sizes, int n_in,
                              void* d_out, int out_size, void* d_ws, size_t ws_size,
                              hipStream_t stream) {
    const float* weight = (const float*)d_in[0];
    const float* alh    = (const float*)d_in[1];
    const float* bit    = (const float*)d_in[2];
    // d_in[3] = init_weight_bit (unused in forward at init)
    float* out = (float*)d_out;

    fake_quant_kernel<<<OUT_CH, 256, 0, stream>>>(weight, alh, bit, out);
}

// Round 2
// 310.875 us; speedup vs baseline: 1.0198x; 1.0198x over previous
//
#include <hip/hip_runtime.h>
#include <hip/hip_bf16.h>

#define OUT_CH 4096
#define IN_FEAT 11008
#define NVEC (IN_FEAT / 4)   // 2752 float4 per row
#define EPS 1e-5f
#define BIT_BOUND 6.0f

// One block per output channel (row). Row scalars computed once per block.
// Body: explicit 4-deep load batching so each thread has 4 outstanding
// global_load_dwordx4 before any dependent use (ILP + TLP latency hiding).
// 2752 = 2*(4*256) + 2*256 + 192.
__global__ __launch_bounds__(256) void fake_quant_kernel(
    const float* __restrict__ weight,
    const float* __restrict__ alh,
    const float* __restrict__ bit,
    float* __restrict__ out)
{
    const int row = blockIdx.x;

    // Per-row quant params (forward values; STE affects only gradients).
    const float s = fmaxf(alh[row], EPS);
    const float b_eff = fminf(fmaxf(fabsf(bit[row]), 1.0f), BIT_BOUND);
    const float b_r = rintf(b_eff);                        // jnp.round = half-to-even
    const float qmax = fmaxf(exp2f(b_r - 1.0f) - 1.0f, 1.0f);
    const float qmin = -qmax;

    const float4* __restrict__ wrow =
        (const float4*)(weight + (size_t)row * IN_FEAT);
    float4* __restrict__ orow = (float4*)(out + (size_t)row * IN_FEAT);
    const int tid = threadIdx.x;

    // Exact IEEE division (matches np w/scale bit-exactly; rintf = half-even).
    auto q4 = [&](float4 w) -> float4 {
        float4 r;
        r.x = fminf(fmaxf(rintf(w.x / s), qmin), qmax) * s;
        r.y = fminf(fmaxf(rintf(w.y / s), qmin), qmax) * s;
        r.z = fminf(fmaxf(rintf(w.z / s), qmin), qmax) * s;
        r.w = fminf(fmaxf(rintf(w.w / s), qmin), qmax) * s;
        return r;
    };

    // Two batches of 4 loads-then-4 stores: indices tid + {0,256,512,768} + b*1024
    #pragma unroll
    for (int b = 0; b < 2; ++b) {
        const int base = tid + b * 1024;
        float4 w0 = wrow[base];
        float4 w1 = wrow[base + 256];
        float4 w2 = wrow[base + 512];
        float4 w3 = wrow[base + 768];
        orow[base]       = q4(w0);
        orow[base + 256] = q4(w1);
        orow[base + 512] = q4(w2);
        orow[base + 768] = q4(w3);
    }
    // Remainder: 2752 - 2048 = 704 = 2*256 + 192
    {
        const int base = tid + 2048;
        float4 w0 = wrow[base];
        float4 w1 = wrow[base + 256];
        orow[base]       = q4(w0);
        orow[base + 256] = q4(w1);
        if (tid < (NVEC - 2560)) {  // 192 lanes
            float4 w2 = wrow[tid + 2560];
            orow[tid + 2560] = q4(w2);
        }
    }
}

extern "C" void kernel_launch(void* const* d_in, const int* in_sizes, int n_in,
                              void* d_out, int out_size, void* d_ws, size_t ws_size,
                              hipStream_t stream) {
    const float* weight = (const float*)d_in[0];
    const float* alh    = (const float*)d_in[1];
    const float* bit    = (const float*)d_in[2];
    // d_in[3] = init_weight_bit (unused in forward at init)
    float* out = (float*)d_out;

    fake_quant_kernel<<<OUT_CH, 256, 0, stream>>>(weight, alh, bit, out);
}

// Round 4
// 294.185 us; speedup vs baseline: 1.0776x; 1.0567x over previous
//
#include <hip/hip_runtime.h>
#include <hip/hip_bf16.h>

#define OUT_CH 4096
#define IN_FEAT 11008
#define NVEC (IN_FEAT / 4)   // 2752 float4 per row
#define EPS 1e-5f
#define BIT_BOUND 6.0f

// Native clang vector type — accepted by __builtin_nontemporal_{load,store}
// (HIP's float4 is a struct and is rejected).
typedef float fvec4 __attribute__((ext_vector_type(4)));

// One block per output channel (row). Row scalars computed once per block.
// Streaming access: non-temporal loads/stores (no reuse -> don't pollute
// L2/LLC, 'nt' flag), 8-deep load batches (8 outstanding
// global_load_dwordx4 per thread). 2752 = 8*256 + 2*256 + 192.
__global__ __launch_bounds__(256) void fake_quant_kernel(
    const float* __restrict__ weight,
    const float* __restrict__ alh,
    const float* __restrict__ bit,
    float* __restrict__ out)
{
    const int row = blockIdx.x;

    // Per-row quant params (forward values; STE affects only gradients).
    const float s = fmaxf(alh[row], EPS);
    const float b_eff = fminf(fmaxf(fabsf(bit[row]), 1.0f), BIT_BOUND);
    const float b_r = rintf(b_eff);                        // jnp.round = half-to-even
    const float qmax = fmaxf(exp2f(b_r - 1.0f) - 1.0f, 1.0f);
    const float qmin = -qmax;

    const fvec4* __restrict__ wrow =
        (const fvec4*)(weight + (size_t)row * IN_FEAT);
    fvec4* __restrict__ orow = (fvec4*)(out + (size_t)row * IN_FEAT);
    const int tid = threadIdx.x;

    // Exact IEEE division (matches np w/scale bit-exactly; rintf = half-even).
    auto q4 = [&](fvec4 w) -> fvec4 {
        fvec4 r;
        r.x = fminf(fmaxf(rintf(w.x / s), qmin), qmax) * s;
        r.y = fminf(fmaxf(rintf(w.y / s), qmin), qmax) * s;
        r.z = fminf(fmaxf(rintf(w.z / s), qmin), qmax) * s;
        r.w = fminf(fmaxf(rintf(w.w / s), qmin), qmax) * s;
        return r;
    };

    // Batch of 8: indices tid + {0..7}*256
    {
        fvec4 w[8];
        #pragma unroll
        for (int j = 0; j < 8; ++j)
            w[j] = __builtin_nontemporal_load(&wrow[tid + j * 256]);
        #pragma unroll
        for (int j = 0; j < 8; ++j)
            __builtin_nontemporal_store(q4(w[j]), &orow[tid + j * 256]);
    }
    // Remainder: 2752 - 2048 = 704 = 2*256 + 192
    {
        fvec4 w0 = __builtin_nontemporal_load(&wrow[tid + 2048]);
        fvec4 w1 = __builtin_nontemporal_load(&wrow[tid + 2304]);
        __builtin_nontemporal_store(q4(w0), &orow[tid + 2048]);
        __builtin_nontemporal_store(q4(w1), &orow[tid + 2304]);
        if (tid < (NVEC - 2560)) {  // 192 lanes
            fvec4 w2 = __builtin_nontemporal_load(&wrow[tid + 2560]);
            __builtin_nontemporal_store(q4(w2), &orow[tid + 2560]);
        }
    }
}

extern "C" void kernel_launch(void* const* d_in, const int* in_sizes, int n_in,
                              void* d_out, int out_size, void* d_ws, size_t ws_size,
                              hipStream_t stream) {
    const float* weight = (const float*)d_in[0];
    const float* alh    = (const float*)d_in[1];
    const float* bit    = (const float*)d_in[2];
    // d_in[3] = init_weight_bit (unused in forward at init)
    float* out = (float*)d_out;

    fake_quant_kernel<<<OUT_CH, 256, 0, stream>>>(weight, alh, bit, out);
}